// Round 1
// baseline (69.189 us; speedup 1.0000x reference)
//
#include <hip/hip_runtime.h>
#include <math.h>

// ---- problem constants -------------------------------------------------
#define BB   4      // batch
#define NN   128    // sites
#define NPP  16     // pores
#define EEE  1280   // ss edges
#define ESP  1024   // sp/ps edges
#define DD   32     // node feat dim
#define CC   16     // gaussian centers / edge feat dim
#define OO   32     // message dim
#define FIN  80     // 2*DD + CC
#define MMM  64     // head hidden
#define TT   3      // message passing steps

// ---- workspace layout (floats) ----------------------------------------
constexpr int OFF_S   = 0;
constexpr int OFF_SP  = OFF_S   + BB*NN*DD;     // 16384
constexpr int OFF_BE  = OFF_SP  + BB*NPP*DD;    // 18432
constexpr int OFF_BSP = OFF_BE  + BB*EEE*CC;    // 100352
constexpr int OFF_BPS = OFF_BSP + BB*ESP*CC;    // 165888
constexpr int OFF_MSS = OFF_BPS + BB*ESP*CC;    // 231424
constexpr int OFF_MPS = OFF_MSS + TT*BB*NN*OO;  // +49152
constexpr int OFF_MSP = OFF_MPS + TT*BB*NN*OO;  // +49152
constexpr int WS_TOTAL = OFF_MSP + TT*BB*NPP*OO;
constexpr int ZM = WS_TOTAL - OFF_MSS;          // zeroed message region

__device__ __forceinline__ float lrelu(float x) { return x > 0.f ? x : 0.01f * x; }

__device__ __forceinline__ void edge_embed(float d, const float* W, const float* bvec, float* out) {
    float g[CC];
#pragma unroll
    for (int c = 0; c < CC; ++c) {
        float mu = (10.0f / 15.0f) * (float)c;  // linspace(0,10,16)
        float z = d - mu;                        // WIDTH = 1.0
        g[c] = expf(-z * z);
    }
#pragma unroll
    for (int j = 0; j < CC; ++j) {
        float a = bvec[j];
#pragma unroll
        for (int c = 0; c < CC; ++c) a += g[c] * W[c * CC + j];
        out[j] = lrelu(a);
    }
}

// ---- K0: zero message buffers + all embeddings -------------------------
__global__ __launch_bounds__(256) void k_init(
    const float* sites, const float* bonds, const float* sites_p,
    const float* bonds_sp, const float* bonds_ps,
    const float* se_W, const float* se_b, const float* sep_W, const float* sep_b,
    const float* ee_W, const float* ee_b, const float* eep_W, const float* eep_b,
    float* ws)
{
    const int total = ZM + BB*NN + BB*NPP + BB*EEE + BB*ESP + BB*ESP;
    for (int i = blockIdx.x * blockDim.x + threadIdx.x; i < total; i += gridDim.x * blockDim.x) {
        int r = i;
        if (r < ZM) { ws[OFF_MSS + r] = 0.f; continue; }
        r -= ZM;
        if (r < BB*NN) {   // site embedding: [B,N,1] @ [1,32]
            float x = sites[r];
            float* o = ws + OFF_S + r * DD;
#pragma unroll
            for (int d = 0; d < DD; ++d) o[d] = lrelu(x * se_W[d] + se_b[d]);
            continue;
        }
        r -= BB*NN;
        if (r < BB*NPP) {  // pore embedding: [B,Np,2] @ [2,32]
            float x0 = sites_p[r * 2], x1 = sites_p[r * 2 + 1];
            float* o = ws + OFF_SP + r * DD;
#pragma unroll
            for (int d = 0; d < DD; ++d) o[d] = lrelu(x0 * sep_W[d] + x1 * sep_W[DD + d] + sep_b[d]);
            continue;
        }
        r -= BB*NPP;
        if (r < BB*EEE) { edge_embed(bonds[r],    ee_W,  ee_b,  ws + OFF_BE  + r * CC); continue; }
        r -= BB*EEE;
        if (r < BB*ESP) { edge_embed(bonds_sp[r], eep_W, eep_b, ws + OFF_BSP + r * CC); continue; }
        r -= BB*ESP;
        edge_embed(bonds_ps[r], eep_W, eep_b, ws + OFF_BPS + r * CC);
    }
}

// ---- K1: all three message streams, one kernel -------------------------
// block = 256 threads = 8 edges x 32 lanes(=O). Per edge: u = lrelu(v@(W1+W2)+b),
// gate = sigmoid(u.aw+ab), atomicAdd m[recv] += gate*u.
__global__ __launch_bounds__(256) void k_edges(
    const float* eqW1_ss, const float* eqW2_ss, const float* eqb_ss, const float* aw_ss, const float* ab_ss,
    const float* eqW1_ps, const float* eqW2_ps, const float* eqb_ps, const float* aw_ps, const float* ab_ps,
    const float* eqW1_sp, const float* eqW2_sp, const float* eqb_sp, const float* aw_sp, const float* ab_sp,
    const int* idx1, const int* idx2, const int* idx1_sp, const int* idx2_sp,
    const int* idx1_ps, const int* idx2_ps,
    float* ws, int t)
{
    __shared__ float sW[FIN * OO];     // W1+W2 combined
    __shared__ float sB[OO], sAw[OO];
    __shared__ float sAb;
    __shared__ float sV[8 * FIN];      // 8 edges' input rows

    const int tid = threadIdx.x;
    const int blk = blockIdx.x;

    const float *W1, *W2, *bias, *aw, *ab;
    const float *pA, *pB, *pE;
    const int *ia, *ib;
    float* mout;
    int nrecv, ne, nA, nB, geb;

    constexpr int NB_SS = BB * EEE / 8;  // 640
    constexpr int NB_PS = BB * ESP / 8;  // 512

    if (blk < NB_SS) {                 // ss: s[idx1], s[idx2], be -> recv sites
        geb = blk * 8; ne = EEE; nA = NN; nB = NN; nrecv = NN;
        ia = idx1; ib = idx2;
        pA = ws + OFF_S; pB = ws + OFF_S; pE = ws + OFF_BE;
        W1 = eqW1_ss + t*FIN*OO; W2 = eqW2_ss + t*FIN*OO;
        bias = eqb_ss + t*OO; aw = aw_ss + t*OO; ab = ab_ss + t;
        mout = ws + OFF_MSS + t*BB*NN*OO;
    } else if (blk < NB_SS + NB_PS) {  // ps: sp[idx1_ps], s[idx2_ps], bps -> recv sites
        geb = (blk - NB_SS) * 8; ne = ESP; nA = NPP; nB = NN; nrecv = NN;
        ia = idx1_ps; ib = idx2_ps;
        pA = ws + OFF_SP; pB = ws + OFF_S; pE = ws + OFF_BPS;
        W1 = eqW1_ps + t*FIN*OO; W2 = eqW2_ps + t*FIN*OO;
        bias = eqb_ps + t*OO; aw = aw_ps + t*OO; ab = ab_ps + t;
        mout = ws + OFF_MPS + t*BB*NN*OO;
    } else {                           // sp: s[idx1_sp], sp[idx2_sp], bsp -> recv pores
        geb = (blk - NB_SS - NB_PS) * 8; ne = ESP; nA = NN; nB = NPP; nrecv = NPP;
        ia = idx1_sp; ib = idx2_sp;
        pA = ws + OFF_S; pB = ws + OFF_SP; pE = ws + OFF_BSP;
        W1 = eqW1_sp + t*FIN*OO; W2 = eqW2_sp + t*FIN*OO;
        bias = eqb_sp + t*OO; aw = aw_sp + t*OO; ab = ab_sp + t;
        mout = ws + OFF_MSP + t*BB*NPP*OO;
    }

    const int b     = geb / ne;        // 8-edge blocks never straddle a batch
    const int ebase = geb % ne;
    const float* pA_b = pA + b * nA * DD;
    const float* pB_b = pB + b * nB * DD;
    const float* pE_b = pE + b * ne * CC;
    float*       m_b  = mout + b * nrecv * OO;

    for (int i = tid; i < FIN * OO; i += 256) sW[i] = W1[i] + W2[i];
    if (tid < OO) { sB[tid] = bias[tid]; sAw[tid] = aw[tid]; }
    if (tid == 0) sAb = ab[0];

    for (int i = tid; i < 8 * FIN; i += 256) {
        int el = i / FIN, f = i % FIN;
        int e = ebase + el;
        float v;
        if (f < DD)           v = pA_b[ia[e] * DD + f];
        else if (f < 2 * DD)  v = pB_b[ib[e] * DD + (f - DD)];
        else                  v = pE_b[e * CC + (f - 2 * DD)];
        sV[i] = v;
    }
    __syncthreads();

    const int el = tid >> 5;
    const int o  = tid & 31;
    const float* v = sV + el * FIN;
    float acc = sB[o];
#pragma unroll
    for (int f = 0; f < FIN; ++f) acc += v[f] * sW[f * OO + o];
    float u = lrelu(acc);

    float r = u * sAw[o];
#pragma unroll
    for (int m = 16; m > 0; m >>= 1) r += __shfl_xor(r, m, 32);
    float gate = 1.f / (1.f + expf(-(r + sAb)));

    int recv = ib[ebase + el];
    atomicAdd(&m_b[recv * OO + o], gate * u);
}

// ---- K2: node updates (sites + pores fused) ----------------------------
__global__ __launch_bounds__(256) void k_nodes(
    const float* nuW1, const float* nub1, const float* nuW2, const float* nub2,
    const float* nupW1, const float* nupb1, const float* nupW2, const float* nupb2,
    float* ws, int t)
{
    __shared__ float sW1[96 * 32];
    __shared__ float sW2[32 * 32];
    __shared__ float sb1[32], sb2[32];
    __shared__ float sh[8 * 96];
    __shared__ float su[8 * 32];

    const int tid = threadIdx.x;
    const int blk = blockIdx.x;
    float* s  = ws + OFF_S;
    float* sp = ws + OFF_SP;
    const float* mss = ws + OFF_MSS + t * BB * NN * OO;
    const float* mps = ws + OFF_MPS + t * BB * NN * OO;
    const float* msp = ws + OFF_MSP + t * BB * NPP * OO;

    const int el = tid >> 5;
    const int o  = tid & 31;

    if (blk < 64) {  // sites: 512 nodes, 8 per block; h = [s, m_ss, m_ps] (96)
        const float* W1 = nuW1 + t * 96 * 32;
        const float* W2 = nuW2 + t * 32 * 32;
        for (int i = tid; i < 96 * 32; i += 256) sW1[i] = W1[i];
        for (int i = tid; i < 32 * 32; i += 256) sW2[i] = W2[i];
        if (tid < 32) { sb1[tid] = nub1[t * 32 + tid]; sb2[tid] = nub2[t * 32 + tid]; }
        for (int i = tid; i < 8 * 96; i += 256) {
            int e2 = i / 96, f = i % 96;
            int g = blk * 8 + e2;       // g = b*NN + n (flat)
            float v;
            if (f < 32)      v = s[g * DD + f];
            else if (f < 64) v = mss[g * OO + (f - 32)];
            else             v = mps[g * OO + (f - 64)];
            sh[i] = v;
        }
        __syncthreads();
        float acc = sb1[o];
#pragma unroll
        for (int f = 0; f < 96; ++f) acc += sh[el * 96 + f] * sW1[f * 32 + o];
        su[el * 32 + o] = lrelu(acc);
        __syncthreads();
        float acc2 = sb2[o];
#pragma unroll
        for (int k = 0; k < 32; ++k) acc2 += su[el * 32 + k] * sW2[k * 32 + o];
        int g = blk * 8 + el;
        s[g * DD + o] += lrelu(acc2);
    } else {         // pores: 64 nodes, 8 per block; h = [sp, m_sp] (64)
        const int blk2 = blk - 64;
        const float* W1 = nupW1 + t * 64 * 32;
        const float* W2 = nupW2 + t * 32 * 32;
        for (int i = tid; i < 64 * 32; i += 256) sW1[i] = W1[i];
        for (int i = tid; i < 32 * 32; i += 256) sW2[i] = W2[i];
        if (tid < 32) { sb1[tid] = nupb1[t * 32 + tid]; sb2[tid] = nupb2[t * 32 + tid]; }
        for (int i = tid; i < 8 * 64; i += 256) {
            int e2 = i / 64, f = i % 64;
            int g = blk2 * 8 + e2;      // g = b*NPP + p (flat)
            float v;
            if (f < 32) v = sp[g * DD + f];
            else        v = msp[g * OO + (f - 32)];
            sh[i] = v;
        }
        __syncthreads();
        float acc = sb1[o];
#pragma unroll
        for (int f = 0; f < 64; ++f) acc += sh[el * 64 + f] * sW1[f * 32 + o];
        su[el * 32 + o] = lrelu(acc);
        __syncthreads();
        float acc2 = sb2[o];
#pragma unroll
        for (int k = 0; k < 32; ++k) acc2 += su[el * 32 + k] * sW2[k * 32 + o];
        int g = blk2 * 8 + el;
        sp[g * DD + o] += lrelu(acc2);
    }
}

// ---- K3: pooling + MLP head (one block per batch) ----------------------
__global__ __launch_bounds__(256) void k_head(
    const float* p1W, const float* p1b, const float* p2aW, const float* p2ab,
    const float* p2bW, const float* p2bb, const float* p3W, const float* p3b,
    const float* ws, float* out)
{
    __shared__ float sS[NN * DD];
    __shared__ float sW[DD * MMM];
    __shared__ float part[4][MMM];
    __shared__ float xv[MMM], yv[MMM], zv[MMM];

    const int b = blockIdx.x;
    const int tid = threadIdx.x;
    const float* s = ws + OFF_S + b * NN * DD;

    for (int i = tid; i < NN * DD; i += 256) sS[i] = s[i];
    for (int i = tid; i < DD * MMM; i += 256) sW[i] = p1W[i];
    __syncthreads();

    const int m = tid & 63;
    const int q = tid >> 6;
    float accp = 0.f;
    for (int n = q * 32; n < q * 32 + 32; ++n) {
        float a = p1b[m];
#pragma unroll
        for (int d = 0; d < DD; ++d) a += sS[n * DD + d] * sW[d * MMM + m];
        accp += lrelu(a);
    }
    part[q][m] = accp;
    __syncthreads();

    if (tid < MMM) xv[tid] = part[0][tid] + part[1][tid] + part[2][tid] + part[3][tid];
    __syncthreads();
    if (tid < MMM) {
        float a = p2ab[tid];
#pragma unroll
        for (int k = 0; k < MMM; ++k) a += xv[k] * p2aW[k * MMM + tid];
        yv[tid] = lrelu(a);
    }
    __syncthreads();
    if (tid < MMM) {
        float a = p2bb[tid];
#pragma unroll
        for (int k = 0; k < MMM; ++k) a += yv[k] * p2bW[k * MMM + tid];
        zv[tid] = lrelu(a);
    }
    __syncthreads();
    if (tid == 0) {
        float a = p3b[0];
#pragma unroll
        for (int k = 0; k < MMM; ++k) a += zv[k] * p3W[k];
        out[b] = a;
    }
}

// ---- launch ------------------------------------------------------------
extern "C" void kernel_launch(void* const* d_in, const int* in_sizes, int n_in,
                              void* d_out, int out_size, void* d_ws, size_t ws_size,
                              hipStream_t stream) {
    const float* sites    = (const float*)d_in[0];
    const float* bonds    = (const float*)d_in[1];
    const float* sites_p  = (const float*)d_in[2];
    const float* bonds_sp = (const float*)d_in[3];
    const float* bonds_ps = (const float*)d_in[4];
    const int* idx1    = (const int*)d_in[5];
    const int* idx2    = (const int*)d_in[6];
    const int* idx1_sp = (const int*)d_in[7];
    const int* idx2_sp = (const int*)d_in[8];
    const int* idx1_ps = (const int*)d_in[9];
    const int* idx2_ps = (const int*)d_in[10];
    const float* se_W  = (const float*)d_in[11];
    const float* se_b  = (const float*)d_in[12];
    const float* sep_W = (const float*)d_in[13];
    const float* sep_b = (const float*)d_in[14];
    const float* ee_W  = (const float*)d_in[15];
    const float* ee_b  = (const float*)d_in[16];
    const float* eep_W = (const float*)d_in[17];
    const float* eep_b = (const float*)d_in[18];
    const float* eqW1_ss = (const float*)d_in[19];
    const float* eqW2_ss = (const float*)d_in[20];
    const float* eqb_ss  = (const float*)d_in[21];
    const float* aw_ss   = (const float*)d_in[22];
    const float* ab_ss   = (const float*)d_in[23];
    const float* eqW1_ps = (const float*)d_in[24];
    const float* eqW2_ps = (const float*)d_in[25];
    const float* eqb_ps  = (const float*)d_in[26];
    const float* aw_ps   = (const float*)d_in[27];
    const float* ab_ps   = (const float*)d_in[28];
    const float* eqW1_sp = (const float*)d_in[29];
    const float* eqW2_sp = (const float*)d_in[30];
    const float* eqb_sp  = (const float*)d_in[31];
    const float* aw_sp   = (const float*)d_in[32];
    const float* ab_sp   = (const float*)d_in[33];
    const float* nuW1  = (const float*)d_in[34];
    const float* nub1  = (const float*)d_in[35];
    const float* nuW2  = (const float*)d_in[36];
    const float* nub2  = (const float*)d_in[37];
    const float* nupW1 = (const float*)d_in[38];
    const float* nupb1 = (const float*)d_in[39];
    const float* nupW2 = (const float*)d_in[40];
    const float* nupb2 = (const float*)d_in[41];
    const float* p1W  = (const float*)d_in[42];
    const float* p1b  = (const float*)d_in[43];
    const float* p2aW = (const float*)d_in[44];
    const float* p2ab = (const float*)d_in[45];
    const float* p2bW = (const float*)d_in[46];
    const float* p2bb = (const float*)d_in[47];
    const float* p3W  = (const float*)d_in[48];
    const float* p3b  = (const float*)d_in[49];

    float* ws  = (float*)d_ws;
    float* out = (float*)d_out;

    const int init_work = ZM + BB*NN + BB*NPP + BB*EEE + BB*ESP + BB*ESP;
    const int init_blocks = (init_work + 255) / 256;

    k_init<<<init_blocks, 256, 0, stream>>>(sites, bonds, sites_p, bonds_sp, bonds_ps,
                                            se_W, se_b, sep_W, sep_b, ee_W, ee_b, eep_W, eep_b, ws);

    const int edge_blocks = BB*EEE/8 + BB*ESP/8 + BB*ESP/8;  // 1664
    for (int t = 0; t < TT; ++t) {
        k_edges<<<edge_blocks, 256, 0, stream>>>(
            eqW1_ss, eqW2_ss, eqb_ss, aw_ss, ab_ss,
            eqW1_ps, eqW2_ps, eqb_ps, aw_ps, ab_ps,
            eqW1_sp, eqW2_sp, eqb_sp, aw_sp, ab_sp,
            idx1, idx2, idx1_sp, idx2_sp, idx1_ps, idx2_ps, ws, t);
        k_nodes<<<72, 256, 0, stream>>>(nuW1, nub1, nuW2, nub2,
                                        nupW1, nupb1, nupW2, nupb2, ws, t);
    }
    k_head<<<4, 256, 0, stream>>>(p1W, p1b, p2aW, p2ab, p2bW, p2bb, p3W, p3b, ws, out);
}